// Round 1
// baseline (672.892 us; speedup 1.0000x reference)
//
#include <hip/hip_runtime.h>

// Problem constants
#define S_ 16
#define B_ 8
#define L_ 8
#define V_ 32000
#define D_ 1024
#define T_ 512
#define G_ 3
#define M_ 1024          // B*S*L fused row count, m = ((b*S + s)*L + l)
#define E3_ 3072         // 3*D

typedef unsigned short U16;
typedef __attribute__((ext_vector_type(8))) short short8;
typedef __attribute__((ext_vector_type(4))) float f32x4;

// ---------- bf16 helpers (RTNE) ----------
__device__ __forceinline__ U16 f2bf(float f) {
  union { float f; unsigned u; } c; c.f = f;
  unsigned u = c.u;
  return (U16)((u + 0x7FFFu + ((u >> 16) & 1u)) >> 16);
}
__device__ __forceinline__ float bf2f(U16 h) {
  union { unsigned u; float f; } c; c.u = ((unsigned)h) << 16;
  return c.f;
}
__device__ __forceinline__ void split2(float f, U16& hi, U16& lo) {
  hi = f2bf(f);
  lo = f2bf(f - bf2f(hi));
}

// ---------- cast kernels ----------
__global__ void k_cast_emb(const float* __restrict__ emb, U16* __restrict__ emb_bf) {
  int idx = blockIdx.x * 256 + threadIdx.x;      // < V_*D_/4
  float4 v = ((const float4*)emb)[idx];
  ushort4 o;
  o.x = f2bf(v.x); o.y = f2bf(v.y); o.z = f2bf(v.z); o.w = f2bf(v.w);
  ((ushort4*)emb_bf)[idx] = o;
}

__global__ void k_cast_wih(const float* __restrict__ w, U16* __restrict__ wh, U16* __restrict__ wl) {
  int idx = blockIdx.x * 256 + threadIdx.x;      // < E3_*D_/4
  float4 v = ((const float4*)w)[idx];
  ushort4 h4, l4;
  split2(v.x, h4.x, l4.x); split2(v.y, h4.y, l4.y);
  split2(v.z, h4.z, l4.z); split2(v.w, h4.w, l4.w);
  ((ushort4*)wh)[idx] = h4;
  ((ushort4*)wl)[idx] = l4;
}

// enc (B,T,D) -> enc_h/l (B,T,D) and transposed encT_h/l (B,D,T)
__global__ void k_cast_enc(const float* __restrict__ enc,
                           U16* __restrict__ enc_h, U16* __restrict__ enc_l,
                           U16* __restrict__ encT_h, U16* __restrict__ encT_l) {
  __shared__ U16 hs[32][36];
  __shared__ U16 ls[32][36];
  int b = blockIdx.z, t0 = blockIdx.x * 32, d0 = blockIdx.y * 32;
  int r  = threadIdx.x >> 3;
  int c4 = (threadIdx.x & 7) * 4;
  size_t src_idx = ((size_t)(b * T_ + t0 + r)) * D_ + d0 + c4;
  float4 v = *(const float4*)(enc + src_idx);
  ushort4 h4, l4;
  split2(v.x, h4.x, l4.x); split2(v.y, h4.y, l4.y);
  split2(v.z, h4.z, l4.z); split2(v.w, h4.w, l4.w);
  *(ushort4*)(enc_h + src_idx) = h4;
  *(ushort4*)(enc_l + src_idx) = l4;
  hs[r][c4+0] = h4.x; hs[r][c4+1] = h4.y; hs[r][c4+2] = h4.z; hs[r][c4+3] = h4.w;
  ls[r][c4+0] = l4.x; ls[r][c4+1] = l4.y; ls[r][c4+2] = l4.z; ls[r][c4+3] = l4.w;
  __syncthreads();
  ushort4 th, tl;
  th.x = hs[c4+0][r]; th.y = hs[c4+1][r]; th.z = hs[c4+2][r]; th.w = hs[c4+3][r];
  tl.x = ls[c4+0][r]; tl.y = ls[c4+1][r]; tl.z = ls[c4+2][r]; tl.w = ls[c4+3][r];
  size_t dst_idx = ((size_t)(b * D_ + d0 + r)) * T_ + t0 + c4;
  *(ushort4*)(encT_h + dst_idx) = th;
  *(ushort4*)(encT_l + dst_idx) = tl;
}

// x[m,:] = (l==0) ? slot_emb[s] : embedding[trg[b,s,l-1]]
__global__ void k_build_x(const float* __restrict__ emb, const float* __restrict__ slot_emb,
                          const int* __restrict__ trg, float* __restrict__ x,
                          U16* __restrict__ x_h, U16* __restrict__ x_l) {
  int m = blockIdx.x;
  int d = threadIdx.x * 4;
  int b = m >> 7, s = (m >> 3) & 15, l = m & 7;
  const float* src;
  if (l == 0) src = slot_emb + s * D_;
  else        src = emb + (size_t)trg[b * (S_ * L_) + s * L_ + (l - 1)] * D_;
  float4 v = *(const float4*)(src + d);
  *(float4*)(x + (size_t)m * D_ + d) = v;
  ushort4 h4, l4;
  split2(v.x, h4.x, l4.x); split2(v.y, h4.y, l4.y);
  split2(v.z, h4.z, l4.z); split2(v.w, h4.w, l4.w);
  *(ushort4*)(x_h + (size_t)m * D_ + d) = h4;
  *(ushort4*)(x_l + (size_t)m * D_ + d) = l4;
}

// gh[b,e] = sum_d h0[b,d]*w_hh[e,d] + b_hh[e]   (fp32 exact path)
__global__ void k_gh(const float* __restrict__ h0, const float* __restrict__ w_hh,
                     const float* __restrict__ b_hh, float* __restrict__ gh) {
  int b = blockIdx.y;
  int e = blockIdx.x * 64 + (threadIdx.x >> 2);
  int part = threadIdx.x & 3;
  const float* hr = h0 + b * D_ + part * 256;
  const float* wr = w_hh + (size_t)e * D_ + part * 256;
  float s = 0.f;
  for (int i = 0; i < 256; ++i) s += hr[i] * wr[i];
  s += __shfl_xor(s, 1);
  s += __shfl_xor(s, 2);
  if (part == 0) gh[b * E3_ + e] = s + b_hh[e];
}

// ---------- MFMA GEMM: C[m,n] = sum_k A[m,k]*B[n,k], 128x128 tile, BK=32 ----------
__device__ __forceinline__ void stage_tile(U16* __restrict__ sm, const U16* __restrict__ g,
                                           int row0, int k0, int lda, int tid) {
#pragma unroll
  for (int i = 0; i < 2; ++i) {
    int o = (i * 256 + tid) * 16;                 // byte offset in 8KB tile
    int row = o >> 6;                             // 64B per row (32 bf16)
    int chunk = ((o >> 4) & 3) ^ ((row >> 1) & 3); // XOR swizzle of 16B chunks
    const U16* gp = g + (size_t)(row0 + row) * lda + k0 + chunk * 8;
    U16* sp = sm + (o >> 1);
    __builtin_amdgcn_global_load_lds((const __attribute__((address_space(1))) unsigned int*)gp,
                                     (__attribute__((address_space(3))) unsigned int*)sp,
                                     16, 0, 0);
  }
}

__device__ __forceinline__ short8 frag_ld(const U16* __restrict__ sm, int rowbase, int ln) {
  int row = rowbase + (ln & 15);
  int chunk = (ln >> 4) ^ ((row >> 1) & 3);
  return *(const short8*)(sm + row * 32 + chunk * 8);
}

template <bool HILO, bool VOCAB>
__global__ __launch_bounds__(256, 2)
void k_gemm(const U16* __restrict__ Ah, const U16* __restrict__ Al,
            const U16* __restrict__ Bh, const U16* __restrict__ Bl,
            float* __restrict__ C, float* __restrict__ rowsum,
            int Ktot, int lda, int ldb, int ldc,
            long sA, long sB, long sC) {
  __shared__ U16 smem[(HILO ? 4 : 2) * 128 * 32];
  U16* Ash = smem;
  U16* Bsh = smem + 4096;
  U16* Asl = HILO ? (smem + 8192) : smem;
  U16* Bsl = HILO ? (smem + 12288) : smem;

  int tid = threadIdx.x;
  int ln = tid & 63, w = tid >> 6;
  int wr = (w >> 1) * 64, wc = (w & 1) * 64;
  int n0 = blockIdx.x * 128, m0 = blockIdx.y * 128;
  int bz = blockIdx.z;
  const U16* pAh = Ah + (size_t)bz * sA;
  const U16* pBh = Bh + (size_t)bz * sB;
  const U16* pAl = HILO ? (Al + (size_t)bz * sA) : nullptr;
  const U16* pBl = HILO ? (Bl + (size_t)bz * sB) : nullptr;

  f32x4 acc[4][4];
#pragma unroll
  for (int i = 0; i < 4; i++)
#pragma unroll
    for (int j = 0; j < 4; j++) acc[i][j] = (f32x4)(0.f);

  for (int k0 = 0; k0 < Ktot; k0 += 32) {
    __syncthreads();                        // protect LDS from prior reads
    stage_tile(Ash, pAh, m0, k0, lda, tid);
    stage_tile(Bsh, pBh, n0, k0, ldb, tid);
    if constexpr (HILO) {
      stage_tile(Asl, pAl, m0, k0, lda, tid);
      stage_tile(Bsl, pBl, n0, k0, ldb, tid);
    }
    __syncthreads();                        // drains vmcnt(0) incl. global_load_lds

    short8 a_h[4], b_h[4];
#pragma unroll
    for (int i = 0; i < 4; i++) {
      a_h[i] = frag_ld(Ash, wr + i * 16, ln);
      b_h[i] = frag_ld(Bsh, wc + i * 16, ln);
    }
    if constexpr (HILO) {
      short8 a_l[4], b_l[4];
#pragma unroll
      for (int i = 0; i < 4; i++) {
        a_l[i] = frag_ld(Asl, wr + i * 16, ln);
        b_l[i] = frag_ld(Bsl, wc + i * 16, ln);
      }
#pragma unroll
      for (int i = 0; i < 4; i++)
#pragma unroll
        for (int j = 0; j < 4; j++) {
          acc[i][j] = __builtin_amdgcn_mfma_f32_16x16x32_bf16(a_h[i], b_h[j], acc[i][j], 0, 0, 0);
          acc[i][j] = __builtin_amdgcn_mfma_f32_16x16x32_bf16(a_h[i], b_l[j], acc[i][j], 0, 0, 0);
          acc[i][j] = __builtin_amdgcn_mfma_f32_16x16x32_bf16(a_l[i], b_h[j], acc[i][j], 0, 0, 0);
        }
    } else {
#pragma unroll
      for (int i = 0; i < 4; i++)
#pragma unroll
        for (int j = 0; j < 4; j++)
          acc[i][j] = __builtin_amdgcn_mfma_f32_16x16x32_bf16(a_h[i], b_h[j], acc[i][j], 0, 0, 0);
    }
  }

  int quad = ln >> 4, col = ln & 15;
  if constexpr (!VOCAB) {
    float* pC = C + (size_t)bz * sC;
#pragma unroll
    for (int i = 0; i < 4; i++)
#pragma unroll
      for (int j = 0; j < 4; j++)
#pragma unroll
        for (int r = 0; r < 4; r++)
          pC[(size_t)(m0 + wr + i * 16 + quad * 4 + r) * ldc + (n0 + wc + j * 16 + col)] =
              acc[i][j][r];
  } else {
    // out[((s*B+b)*L+l)*V + v] = exp(logit); rowsum[m] += partials
#pragma unroll
    for (int i = 0; i < 4; i++)
#pragma unroll
      for (int r = 0; r < 4; r++) {
        int m = m0 + wr + i * 16 + quad * 4 + r;
        int s_ = (m >> 3) & 15, l_ = m & 7, b_ = m >> 7;
        size_t obase = (size_t)((s_ * B_ + b_) * L_ + l_) * (size_t)V_;
        float rs = 0.f;
#pragma unroll
        for (int j = 0; j < 4; j++) {
          float e = __expf(acc[i][j][r]);
          C[obase + (n0 + wc + j * 16 + col)] = e;
          rs += e;
        }
        rs += __shfl_xor(rs, 1);
        rs += __shfl_xor(rs, 2);
        rs += __shfl_xor(rs, 4);
        rs += __shfl_xor(rs, 8);
        if (col == 0) atomicAdd(&rowsum[m], rs);
      }
  }
}

// ---------- GRU pointwise ----------
__global__ void k_h(const float* __restrict__ gi, const float* __restrict__ gh,
                    const float* __restrict__ h0, const float* __restrict__ b_ih,
                    float* __restrict__ h, U16* __restrict__ h_h, U16* __restrict__ h_l) {
  int m = blockIdx.x;
  int d = threadIdx.x * 4;
  int b = m >> 7;
  float4 ir  = *(const float4*)(gi + (size_t)m * E3_ + d);
  float4 iz  = *(const float4*)(gi + (size_t)m * E3_ + D_ + d);
  float4 in_ = *(const float4*)(gi + (size_t)m * E3_ + 2 * D_ + d);
  float4 bir = *(const float4*)(b_ih + d);
  float4 biz = *(const float4*)(b_ih + D_ + d);
  float4 bin = *(const float4*)(b_ih + 2 * D_ + d);
  float4 hr  = *(const float4*)(gh + b * E3_ + d);
  float4 hz  = *(const float4*)(gh + b * E3_ + D_ + d);
  float4 hn  = *(const float4*)(gh + b * E3_ + 2 * D_ + d);
  float4 h0v = *(const float4*)(h0 + b * D_ + d);
  float4 out;
#define GRU1(c)                                             \
  {                                                         \
    float rr = 1.f / (1.f + __expf(-(ir.c + bir.c + hr.c))); \
    float zz = 1.f / (1.f + __expf(-(iz.c + biz.c + hz.c))); \
    float nn = tanhf(in_.c + bin.c + rr * hn.c);            \
    out.c = (1.f - zz) * nn + zz * h0v.c;                   \
  }
  GRU1(x) GRU1(y) GRU1(z) GRU1(w)
#undef GRU1
  *(float4*)(h + (size_t)m * D_ + d) = out;
  ushort4 h4, l4;
  split2(out.x, h4.x, l4.x); split2(out.y, h4.y, l4.y);
  split2(out.z, h4.z, l4.z); split2(out.w, h4.w, l4.w);
  *(ushort4*)(h_h + (size_t)m * D_ + d) = h4;
  *(ushort4*)(h_l + (size_t)m * D_ + d) = l4;
}

// ---------- softmax over T + hi/lo cast of raw scores ----------
__global__ void k_softmax(const float* __restrict__ scores, float* __restrict__ probs,
                          U16* __restrict__ s_h, U16* __restrict__ s_l) {
  int m = blockIdx.x;
  int tid = threadIdx.x;
  int ln = tid & 63, w = tid >> 6;
  float v0 = scores[(size_t)m * T_ + tid];
  float v1 = scores[(size_t)m * T_ + 256 + tid];
  U16 hh, ll;
  split2(v0, hh, ll); s_h[m * T_ + tid] = hh;       s_l[m * T_ + tid] = ll;
  split2(v1, hh, ll); s_h[m * T_ + 256 + tid] = hh; s_l[m * T_ + 256 + tid] = ll;
  float mx = fmaxf(v0, v1);
#pragma unroll
  for (int msk = 32; msk >= 1; msk >>= 1) mx = fmaxf(mx, __shfl_xor(mx, msk));
  __shared__ float red[4];
  if (ln == 0) red[w] = mx;
  __syncthreads();
  mx = fmaxf(fmaxf(red[0], red[1]), fmaxf(red[2], red[3]));
  float e0 = __expf(v0 - mx), e1 = __expf(v1 - mx);
  float sm = e0 + e1;
#pragma unroll
  for (int msk = 32; msk >= 1; msk >>= 1) sm += __shfl_xor(sm, msk);
  __syncthreads();
  if (ln == 0) red[w] = sm;
  __syncthreads();
  float inv = 1.f / (red[0] + red[1] + red[2] + red[3]);
  probs[(size_t)m * T_ + tid] = e0 * inv;
  probs[(size_t)m * T_ + 256 + tid] = e1 * inv;
}

// ---------- p_gen (accurate fp32 dot) + rowsum zeroing ----------
__global__ void k_pgen(const float* __restrict__ h, const float* __restrict__ ctx,
                       const float* __restrict__ x, const float* __restrict__ wr,
                       const float* __restrict__ wrb, float* __restrict__ p_gen,
                       float* __restrict__ rowsum) {
  int m = blockIdx.x;
  int tid = threadIdx.x;
  int ln = tid & 63, w = tid >> 6;
  float sacc = 0.f;
  for (int j = tid; j < D_; j += 256)
    sacc += h[(size_t)m * D_ + j] * wr[j] + ctx[(size_t)m * D_ + j] * wr[D_ + j] +
            x[(size_t)m * D_ + j] * wr[2 * D_ + j];
#pragma unroll
  for (int msk = 32; msk >= 1; msk >>= 1) sacc += __shfl_xor(sacc, msk);
  __shared__ float red[4];
  if (ln == 0) red[w] = sacc;
  __syncthreads();
  if (tid == 0) {
    float t = red[0] + red[1] + red[2] + red[3] + wrb[0];
    p_gen[m] = 1.f / (1.f + expf(-t));
    rowsum[m] = 0.f;
  }
}

// ---------- gate_outputs ----------
__global__ void k_gate(const float* __restrict__ ctx, const float* __restrict__ wg,
                       const float* __restrict__ wgb, float* __restrict__ out_gate) {
  int id = blockIdx.x;                // (s*8+b)*3+g
  int g = id % 3;
  int sb = id / 3;
  int b = sb & 7, s = sb >> 3;
  int m = (b * S_ + s) * L_;          // l = 0
  int ln = threadIdx.x;
  float acc = 0.f;
  for (int d = ln; d < D_; d += 64) acc += ctx[(size_t)m * D_ + d] * wg[g * D_ + d];
#pragma unroll
  for (int msk = 32; msk >= 1; msk >>= 1) acc += __shfl_xor(acc, msk);
  if (ln == 0) out_gate[id] = acc + wgb[g];
}

// ---------- scale out by p_gen/rowsum ----------
__global__ void k_scale(float* __restrict__ out, const float* __restrict__ p_gen,
                        const float* __restrict__ rowsum) {
  int idx = blockIdx.x * 256 + threadIdx.x;  // < M_*V_/4
  int osl = idx / (V_ / 4);
  int s = osl >> 6, b = (osl >> 3) & 7, l = osl & 7;
  int m = (b << 7) | (s << 3) | l;
  float sc = p_gen[m] / rowsum[m];
  float4* p = (float4*)out + idx;
  float4 v = *p;
  v.x *= sc; v.y *= sc; v.z *= sc; v.w *= sc;
  *p = v;
}

// ---------- copy-distribution scatter ----------
__global__ void k_scatter(float* __restrict__ out, const float* __restrict__ p_gen,
                          const float* __restrict__ probs, const int* __restrict__ story) {
  int id = blockIdx.x * 256 + threadIdx.x;  // < M_*T_
  int m = id >> 9, t = id & 511;
  int b = m >> 7, s = (m >> 3) & 15, l = m & 7;
  float val = (1.f - p_gen[m]) * probs[(size_t)m * T_ + t];
  int v = story[b * T_ + t];
  size_t o = (size_t)((s * B_ + b) * L_ + l) * (size_t)V_ + v;
  atomicAdd(out + o, val);
}

extern "C" void kernel_launch(void* const* d_in, const int* in_sizes, int n_in,
                              void* d_out, int out_size, void* d_ws, size_t ws_size,
                              hipStream_t stream) {
  (void)in_sizes; (void)n_in; (void)out_size; (void)ws_size;
  const float* enc_hid   = (const float*)d_in[0];
  const float* enc_out   = (const float*)d_in[1];
  const int*   story     = (const int*)d_in[2];
  const int*   trg       = (const int*)d_in[3];
  const float* emb       = (const float*)d_in[4];
  const float* w_ih      = (const float*)d_in[5];
  const float* w_hh      = (const float*)d_in[6];
  const float* b_ih      = (const float*)d_in[7];
  const float* b_hh      = (const float*)d_in[8];
  const float* w_ratio_w = (const float*)d_in[9];
  const float* w_ratio_b = (const float*)d_in[10];
  const float* w_gate_w  = (const float*)d_in[11];
  const float* w_gate_b  = (const float*)d_in[12];
  const float* slot_emb  = (const float*)d_in[13];
  float* out = (float*)d_out;

  char* ws = (char*)d_ws;
  size_t off = 0;
  auto alloc = [&](size_t bytes) -> void* {
    void* p = ws + off;
    off += (bytes + 255) & ~(size_t)255;
    return p;
  };
  U16* emb_bf   = (U16*)alloc((size_t)V_ * D_ * 2);
  float* x      = (float*)alloc((size_t)M_ * D_ * 4);
  U16* x_h      = (U16*)alloc((size_t)M_ * D_ * 2);
  U16* x_l      = (U16*)alloc((size_t)M_ * D_ * 2);
  U16* wih_h    = (U16*)alloc((size_t)E3_ * D_ * 2);
  U16* wih_l    = (U16*)alloc((size_t)E3_ * D_ * 2);
  U16* enc_h    = (U16*)alloc((size_t)B_ * T_ * D_ * 2);
  U16* enc_l    = (U16*)alloc((size_t)B_ * T_ * D_ * 2);
  U16* encT_h   = (U16*)alloc((size_t)B_ * T_ * D_ * 2);
  U16* encT_l   = (U16*)alloc((size_t)B_ * T_ * D_ * 2);
  float* gh     = (float*)alloc((size_t)B_ * E3_ * 4);
  float* gi     = (float*)alloc((size_t)M_ * E3_ * 4);
  float* h      = (float*)alloc((size_t)M_ * D_ * 4);
  U16* h_h      = (U16*)alloc((size_t)M_ * D_ * 2);
  U16* h_l      = (U16*)alloc((size_t)M_ * D_ * 2);
  float* scores = (float*)alloc((size_t)M_ * T_ * 4);
  U16* sc_h     = (U16*)alloc((size_t)M_ * T_ * 2);
  U16* sc_l     = (U16*)alloc((size_t)M_ * T_ * 2);
  float* probs  = (float*)alloc((size_t)M_ * T_ * 4);
  float* ctx    = (float*)alloc((size_t)M_ * D_ * 4);
  float* p_gen  = (float*)alloc((size_t)M_ * 4);
  float* rowsum = (float*)alloc((size_t)M_ * 4);

  // --- casts / prep ---
  k_cast_emb<<<V_ * D_ / 4 / 256, 256, 0, stream>>>(emb, emb_bf);
  k_cast_wih<<<E3_ * D_ / 4 / 256, 256, 0, stream>>>(w_ih, wih_h, wih_l);
  k_cast_enc<<<dim3(T_ / 32, D_ / 32, B_), 256, 0, stream>>>(enc_out, enc_h, enc_l, encT_h, encT_l);
  k_build_x<<<M_, 256, 0, stream>>>(emb, slot_emb, trg, x, x_h, x_l);
  k_gh<<<dim3(E3_ / 64, B_), 256, 0, stream>>>(enc_hid, w_hh, b_hh, gh);

  // --- gi = x @ w_ih^T (hi/lo) ---
  k_gemm<true, false><<<dim3(E3_ / 128, M_ / 128, 1), 256, 0, stream>>>(
      x_h, x_l, wih_h, wih_l, gi, nullptr, D_, D_, D_, E3_, 0, 0, 0);

  // --- GRU pointwise -> h ---
  k_h<<<M_, 256, 0, stream>>>(gi, gh, enc_hid, b_ih, h, h_h, h_l);

  // --- scores = h @ enc^T per batch (hi/lo) ---
  k_gemm<true, false><<<dim3(T_ / 128, 1, B_), 256, 0, stream>>>(
      h_h, h_l, enc_h, enc_l, scores, nullptr, D_, D_, D_, T_,
      (long)(S_ * L_) * D_, (long)T_ * D_, (long)(S_ * L_) * T_);

  // --- softmax over T + score splits ---
  k_softmax<<<M_, 256, 0, stream>>>(scores, probs, sc_h, sc_l);

  // --- context = scores @ enc per batch (hi/lo, B from transposed enc) ---
  k_gemm<true, false><<<dim3(D_ / 128, 1, B_), 256, 0, stream>>>(
      sc_h, sc_l, encT_h, encT_l, ctx, nullptr, T_, T_, T_, D_,
      (long)(S_ * L_) * T_, (long)D_ * T_, (long)(S_ * L_) * D_);

  // --- p_gen (also zeroes rowsum), gate outputs ---
  k_pgen<<<M_, 256, 0, stream>>>(h, ctx, x, w_ratio_w, w_ratio_b, p_gen, rowsum);
  k_gate<<<S_ * B_ * G_, 64, 0, stream>>>(ctx, w_gate_w, w_gate_b, out + (size_t)M_ * V_);

  // --- vocab GEMM: out = exp(h @ E^T), rowsum accumulated ---
  k_gemm<false, true><<<dim3(V_ / 128, M_ / 128, 1), 256, 0, stream>>>(
      h_h, nullptr, emb_bf, nullptr, out, rowsum, D_, D_, D_, V_, 0, 0, 0);

  // --- out *= p_gen/rowsum ; then scatter copy-probs ---
  k_scale<<<M_ * V_ / 4 / 256, 256, 0, stream>>>(out, p_gen, rowsum);
  k_scatter<<<M_ * T_ / 256, 256, 0, stream>>>(out, p_gen, probs, story);
}

// Round 2
// 593.685 us; speedup vs baseline: 1.1334x; 1.1334x over previous
//
#include <hip/hip_runtime.h>

// Problem constants
#define S_ 16
#define B_ 8
#define L_ 8
#define V_ 32000
#define D_ 1024
#define T_ 512
#define G_ 3
#define M_ 1024          // B*S*L fused row count, m = ((b*S + s)*L + l)
#define E3_ 3072         // 3*D
#define NT_ 250          // V_/128 n-tiles in vocab GEMM

typedef unsigned short U16;
typedef __attribute__((ext_vector_type(8))) short short8;
typedef __attribute__((ext_vector_type(4))) float f32x4;

// ---------- bf16 helpers (RTNE) ----------
__device__ __forceinline__ U16 f2bf(float f) {
  union { float f; unsigned u; } c; c.f = f;
  unsigned u = c.u;
  return (U16)((u + 0x7FFFu + ((u >> 16) & 1u)) >> 16);
}
__device__ __forceinline__ float bf2f(U16 h) {
  union { unsigned u; float f; } c; c.u = ((unsigned)h) << 16;
  return c.f;
}
__device__ __forceinline__ void split2(float f, U16& hi, U16& lo) {
  hi = f2bf(f);
  lo = f2bf(f - bf2f(hi));
}

// ---------- cast kernels ----------
__global__ void k_cast_emb(const float* __restrict__ emb, U16* __restrict__ emb_bf) {
  int idx = blockIdx.x * 256 + threadIdx.x;      // < V_*D_/4
  float4 v = ((const float4*)emb)[idx];
  ushort4 o;
  o.x = f2bf(v.x); o.y = f2bf(v.y); o.z = f2bf(v.z); o.w = f2bf(v.w);
  ((ushort4*)emb_bf)[idx] = o;
}

__global__ void k_cast_wih(const float* __restrict__ w, U16* __restrict__ wh, U16* __restrict__ wl) {
  int idx = blockIdx.x * 256 + threadIdx.x;      // < E3_*D_/4
  float4 v = ((const float4*)w)[idx];
  ushort4 h4, l4;
  split2(v.x, h4.x, l4.x); split2(v.y, h4.y, l4.y);
  split2(v.z, h4.z, l4.z); split2(v.w, h4.w, l4.w);
  ((ushort4*)wh)[idx] = h4;
  ((ushort4*)wl)[idx] = l4;
}

// enc (B,T,D) -> enc_h/l (B,T,D) and transposed encT_h/l (B,D,T)
__global__ void k_cast_enc(const float* __restrict__ enc,
                           U16* __restrict__ enc_h, U16* __restrict__ enc_l,
                           U16* __restrict__ encT_h, U16* __restrict__ encT_l) {
  __shared__ U16 hs[32][36];
  __shared__ U16 ls[32][36];
  int b = blockIdx.z, t0 = blockIdx.x * 32, d0 = blockIdx.y * 32;
  int r  = threadIdx.x >> 3;
  int c4 = (threadIdx.x & 7) * 4;
  size_t src_idx = ((size_t)(b * T_ + t0 + r)) * D_ + d0 + c4;
  float4 v = *(const float4*)(enc + src_idx);
  ushort4 h4, l4;
  split2(v.x, h4.x, l4.x); split2(v.y, h4.y, l4.y);
  split2(v.z, h4.z, l4.z); split2(v.w, h4.w, l4.w);
  *(ushort4*)(enc_h + src_idx) = h4;
  *(ushort4*)(enc_l + src_idx) = l4;
  hs[r][c4+0] = h4.x; hs[r][c4+1] = h4.y; hs[r][c4+2] = h4.z; hs[r][c4+3] = h4.w;
  ls[r][c4+0] = l4.x; ls[r][c4+1] = l4.y; ls[r][c4+2] = l4.z; ls[r][c4+3] = l4.w;
  __syncthreads();
  ushort4 th, tl;
  th.x = hs[c4+0][r]; th.y = hs[c4+1][r]; th.z = hs[c4+2][r]; th.w = hs[c4+3][r];
  tl.x = ls[c4+0][r]; tl.y = ls[c4+1][r]; tl.z = ls[c4+2][r]; tl.w = ls[c4+3][r];
  size_t dst_idx = ((size_t)(b * D_ + d0 + r)) * T_ + t0 + c4;
  *(ushort4*)(encT_h + dst_idx) = th;
  *(ushort4*)(encT_l + dst_idx) = tl;
}

// x[m,:] = (l==0) ? slot_emb[s] : embedding[trg[b,s,l-1]]
__global__ void k_build_x(const float* __restrict__ emb, const float* __restrict__ slot_emb,
                          const int* __restrict__ trg, float* __restrict__ x,
                          U16* __restrict__ x_h, U16* __restrict__ x_l) {
  int m = blockIdx.x;
  int d = threadIdx.x * 4;
  int b = m >> 7, s = (m >> 3) & 15, l = m & 7;
  const float* src;
  if (l == 0) src = slot_emb + s * D_;
  else        src = emb + (size_t)trg[b * (S_ * L_) + s * L_ + (l - 1)] * D_;
  float4 v = *(const float4*)(src + d);
  *(float4*)(x + (size_t)m * D_ + d) = v;
  ushort4 h4, l4;
  split2(v.x, h4.x, l4.x); split2(v.y, h4.y, l4.y);
  split2(v.z, h4.z, l4.z); split2(v.w, h4.w, l4.w);
  *(ushort4*)(x_h + (size_t)m * D_ + d) = h4;
  *(ushort4*)(x_l + (size_t)m * D_ + d) = l4;
}

// gh[b,e] = sum_d h0[b,d]*w_hh[e,d] + b_hh[e]   (fp32 exact path)
__global__ void k_gh(const float* __restrict__ h0, const float* __restrict__ w_hh,
                     const float* __restrict__ b_hh, float* __restrict__ gh) {
  int b = blockIdx.y;
  int e = blockIdx.x * 64 + (threadIdx.x >> 2);
  int part = threadIdx.x & 3;
  const float* hr = h0 + b * D_ + part * 256;
  const float* wr = w_hh + (size_t)e * D_ + part * 256;
  float s = 0.f;
  for (int i = 0; i < 256; ++i) s += hr[i] * wr[i];
  s += __shfl_xor(s, 1);
  s += __shfl_xor(s, 2);
  if (part == 0) gh[b * E3_ + e] = s + b_hh[e];
}

// ---------- MFMA GEMM: C[m,n] = sum_k A[m,k]*B[n,k], 128x128 tile ----------
// BK=32 layout: row = 64B (4 chunks of 16B), chunk XOR (row>>1)&3
// BK=64 layout: row = 128B (8 chunks of 16B), chunk XOR row&7
template <int BK>
__device__ __forceinline__ void stage_tile(U16* __restrict__ sm, const U16* __restrict__ g,
                                           int row0, int k0, int lda, int tid) {
  constexpr int PASSES = (128 * BK * 2) / 4096;   // 256 threads * 16B per pass
#pragma unroll
  for (int i = 0; i < PASSES; ++i) {
    int o = (i * 256 + tid) * 16;                 // byte offset in tile
    int row, gc;
    if constexpr (BK == 32) {
      row = o >> 6;
      gc = ((o >> 4) & 3) ^ ((row >> 1) & 3);
    } else {
      row = o >> 7;
      gc = ((o >> 4) & 7) ^ (row & 7);
    }
    const U16* gp = g + (size_t)(row0 + row) * lda + k0 + gc * 8;
    U16* sp = sm + (o >> 1);
    __builtin_amdgcn_global_load_lds((const __attribute__((address_space(1))) unsigned int*)gp,
                                     (__attribute__((address_space(3))) unsigned int*)sp,
                                     16, 0, 0);
  }
}

template <int BK>
__device__ __forceinline__ short8 frag_ld(const U16* __restrict__ sm, int rowbase, int ln, int kh) {
  int row = rowbase + (ln & 15);
  if constexpr (BK == 32) {
    int c = (ln >> 4) ^ ((row >> 1) & 3);
    return *(const short8*)(sm + row * 32 + c * 8);
  } else {
    int c = (kh * 4 + (ln >> 4)) ^ (row & 7);
    return *(const short8*)(sm + row * 64 + c * 8);
  }
}

template <int BK, bool HILO, bool VOCAB, bool SWAP>
__global__ __launch_bounds__(256, 2)
void k_gemm(const U16* __restrict__ Ah, const U16* __restrict__ Al,
            const U16* __restrict__ Bh, const U16* __restrict__ Bl,
            float* __restrict__ C, float* __restrict__ part,
            int Ktot, int lda, int ldb, int ldc,
            long sA, long sB, long sC) {
  constexpr int TILE_U16 = 128 * BK;
  __shared__ U16 smem[(HILO ? 4 : 2) * TILE_U16];
  __shared__ float rsred[128];
  U16* Ash = smem;
  U16* Bsh = smem + TILE_U16;
  U16* Asl = HILO ? (smem + 2 * TILE_U16) : smem;
  U16* Bsl = HILO ? (smem + 3 * TILE_U16) : smem;

  int tid = threadIdx.x;
  int ln = tid & 63, w = tid >> 6;
  int wr = (w >> 1) * 64, wc = (w & 1) * 64;
  int m0 = (SWAP ? blockIdx.x : blockIdx.y) * 128;
  int n0 = (SWAP ? blockIdx.y : blockIdx.x) * 128;
  int ntile = SWAP ? blockIdx.y : blockIdx.x;
  int bz = blockIdx.z;
  const U16* pAh = Ah + (size_t)bz * sA;
  const U16* pBh = Bh + (size_t)bz * sB;
  const U16* pAl = HILO ? (Al + (size_t)bz * sA) : nullptr;
  const U16* pBl = HILO ? (Bl + (size_t)bz * sB) : nullptr;

  if constexpr (VOCAB) {
    if (tid < 128) rsred[tid] = 0.f;
  }

  f32x4 acc[4][4];
#pragma unroll
  for (int i = 0; i < 4; i++)
#pragma unroll
    for (int j = 0; j < 4; j++) acc[i][j] = (f32x4)(0.f);

  for (int k0 = 0; k0 < Ktot; k0 += BK) {
    __syncthreads();                        // protect LDS from prior reads
    stage_tile<BK>(Ash, pAh, m0, k0, lda, tid);
    stage_tile<BK>(Bsh, pBh, n0, k0, ldb, tid);
    if constexpr (HILO) {
      stage_tile<BK>(Asl, pAl, m0, k0, lda, tid);
      stage_tile<BK>(Bsl, pBl, n0, k0, ldb, tid);
    }
    __syncthreads();                        // drains vmcnt(0) incl. global_load_lds

#pragma unroll
    for (int kh = 0; kh < BK / 32; kh++) {
      short8 a_h[4], b_h[4];
#pragma unroll
      for (int i = 0; i < 4; i++) {
        a_h[i] = frag_ld<BK>(Ash, wr + i * 16, ln, kh);
        b_h[i] = frag_ld<BK>(Bsh, wc + i * 16, ln, kh);
      }
      if constexpr (HILO) {
        short8 a_l[4], b_l[4];
#pragma unroll
        for (int i = 0; i < 4; i++) {
          a_l[i] = frag_ld<BK>(Asl, wr + i * 16, ln, kh);
          b_l[i] = frag_ld<BK>(Bsl, wc + i * 16, ln, kh);
        }
#pragma unroll
        for (int i = 0; i < 4; i++)
#pragma unroll
          for (int j = 0; j < 4; j++) {
            acc[i][j] = __builtin_amdgcn_mfma_f32_16x16x32_bf16(a_h[i], b_h[j], acc[i][j], 0, 0, 0);
            acc[i][j] = __builtin_amdgcn_mfma_f32_16x16x32_bf16(a_h[i], b_l[j], acc[i][j], 0, 0, 0);
            acc[i][j] = __builtin_amdgcn_mfma_f32_16x16x32_bf16(a_l[i], b_h[j], acc[i][j], 0, 0, 0);
          }
      } else {
#pragma unroll
        for (int i = 0; i < 4; i++)
#pragma unroll
          for (int j = 0; j < 4; j++)
            acc[i][j] = __builtin_amdgcn_mfma_f32_16x16x32_bf16(a_h[i], b_h[j], acc[i][j], 0, 0, 0);
      }
    }
  }

  int quad = ln >> 4, col = ln & 15;
  if constexpr (!VOCAB) {
    float* pC = C + (size_t)bz * sC;
#pragma unroll
    for (int i = 0; i < 4; i++)
#pragma unroll
      for (int j = 0; j < 4; j++)
#pragma unroll
        for (int r = 0; r < 4; r++)
          pC[(size_t)(m0 + wr + i * 16 + quad * 4 + r) * ldc + (n0 + wc + j * 16 + col)] =
              acc[i][j][r];
  } else {
    // out[((s*B+b)*L+l)*V + v] = exp(logit); per-(ntile,row) partial sums, no global atomics
#pragma unroll
    for (int i = 0; i < 4; i++)
#pragma unroll
      for (int r = 0; r < 4; r++) {
        int m = m0 + wr + i * 16 + quad * 4 + r;
        int s_ = (m >> 3) & 15, l_ = m & 7, b_ = m >> 7;
        size_t obase = (size_t)((s_ * B_ + b_) * L_ + l_) * (size_t)V_;
        float rs = 0.f;
#pragma unroll
        for (int j = 0; j < 4; j++) {
          float e = __expf(acc[i][j][r]);
          C[obase + (n0 + wc + j * 16 + col)] = e;
          rs += e;
        }
        rs += __shfl_xor(rs, 1);
        rs += __shfl_xor(rs, 2);
        rs += __shfl_xor(rs, 4);
        rs += __shfl_xor(rs, 8);
        if (col == 0) atomicAdd(&rsred[(wr + i * 16 + quad * 4 + r)], rs);  // LDS atomic
      }
    __syncthreads();
    if (tid < 128) part[(size_t)ntile * M_ + (m0 + tid)] = rsred[tid];
  }
}

// ---------- GRU pointwise ----------
__global__ void k_h(const float* __restrict__ gi, const float* __restrict__ gh,
                    const float* __restrict__ h0, const float* __restrict__ b_ih,
                    float* __restrict__ h, U16* __restrict__ h_h, U16* __restrict__ h_l) {
  int m = blockIdx.x;
  int d = threadIdx.x * 4;
  int b = m >> 7;
  float4 ir  = *(const float4*)(gi + (size_t)m * E3_ + d);
  float4 iz  = *(const float4*)(gi + (size_t)m * E3_ + D_ + d);
  float4 in_ = *(const float4*)(gi + (size_t)m * E3_ + 2 * D_ + d);
  float4 bir = *(const float4*)(b_ih + d);
  float4 biz = *(const float4*)(b_ih + D_ + d);
  float4 bin = *(const float4*)(b_ih + 2 * D_ + d);
  float4 hr  = *(const float4*)(gh + b * E3_ + d);
  float4 hz  = *(const float4*)(gh + b * E3_ + D_ + d);
  float4 hn  = *(const float4*)(gh + b * E3_ + 2 * D_ + d);
  float4 h0v = *(const float4*)(h0 + b * D_ + d);
  float4 out;
#define GRU1(c)                                             \
  {                                                         \
    float rr = 1.f / (1.f + __expf(-(ir.c + bir.c + hr.c))); \
    float zz = 1.f / (1.f + __expf(-(iz.c + biz.c + hz.c))); \
    float nn = tanhf(in_.c + bin.c + rr * hn.c);            \
    out.c = (1.f - zz) * nn + zz * h0v.c;                   \
  }
  GRU1(x) GRU1(y) GRU1(z) GRU1(w)
#undef GRU1
  *(float4*)(h + (size_t)m * D_ + d) = out;
  ushort4 h4, l4;
  split2(out.x, h4.x, l4.x); split2(out.y, h4.y, l4.y);
  split2(out.z, h4.z, l4.z); split2(out.w, h4.w, l4.w);
  *(ushort4*)(h_h + (size_t)m * D_ + d) = h4;
  *(ushort4*)(h_l + (size_t)m * D_ + d) = l4;
}

// ---------- softmax over T + hi/lo cast of raw scores ----------
__global__ void k_softmax(const float* __restrict__ scores, float* __restrict__ probs,
                          U16* __restrict__ s_h, U16* __restrict__ s_l) {
  int m = blockIdx.x;
  int tid = threadIdx.x;
  int ln = tid & 63, w = tid >> 6;
  float v0 = scores[(size_t)m * T_ + tid];
  float v1 = scores[(size_t)m * T_ + 256 + tid];
  U16 hh, ll;
  split2(v0, hh, ll); s_h[m * T_ + tid] = hh;       s_l[m * T_ + tid] = ll;
  split2(v1, hh, ll); s_h[m * T_ + 256 + tid] = hh; s_l[m * T_ + 256 + tid] = ll;
  float mx = fmaxf(v0, v1);
#pragma unroll
  for (int msk = 32; msk >= 1; msk >>= 1) mx = fmaxf(mx, __shfl_xor(mx, msk));
  __shared__ float red[4];
  if (ln == 0) red[w] = mx;
  __syncthreads();
  mx = fmaxf(fmaxf(red[0], red[1]), fmaxf(red[2], red[3]));
  float e0 = __expf(v0 - mx), e1 = __expf(v1 - mx);
  float sm = e0 + e1;
#pragma unroll
  for (int msk = 32; msk >= 1; msk >>= 1) sm += __shfl_xor(sm, msk);
  __syncthreads();
  if (ln == 0) red[w] = sm;
  __syncthreads();
  float inv = 1.f / (red[0] + red[1] + red[2] + red[3]);
  probs[(size_t)m * T_ + tid] = e0 * inv;
  probs[(size_t)m * T_ + 256 + tid] = e1 * inv;
}

// ---------- p_gen (accurate fp32 dot) ----------
__global__ void k_pgen(const float* __restrict__ h, const float* __restrict__ ctx,
                       const float* __restrict__ x, const float* __restrict__ wr,
                       const float* __restrict__ wrb, float* __restrict__ p_gen) {
  int m = blockIdx.x;
  int tid = threadIdx.x;
  int ln = tid & 63, w = tid >> 6;
  float sacc = 0.f;
  for (int j = tid; j < D_; j += 256)
    sacc += h[(size_t)m * D_ + j] * wr[j] + ctx[(size_t)m * D_ + j] * wr[D_ + j] +
            x[(size_t)m * D_ + j] * wr[2 * D_ + j];
#pragma unroll
  for (int msk = 32; msk >= 1; msk >>= 1) sacc += __shfl_xor(sacc, msk);
  __shared__ float red[4];
  if (ln == 0) red[w] = sacc;
  __syncthreads();
  if (tid == 0) {
    float t = red[0] + red[1] + red[2] + red[3] + wrb[0];
    p_gen[m] = 1.f / (1.f + expf(-t));
  }
}

// ---------- gate_outputs ----------
__global__ void k_gate(const float* __restrict__ ctx, const float* __restrict__ wg,
                       const float* __restrict__ wgb, float* __restrict__ out_gate) {
  int id = blockIdx.x;                // (s*8+b)*3+g
  int g = id % 3;
  int sb = id / 3;
  int b = sb & 7, s = sb >> 3;
  int m = (b * S_ + s) * L_;          // l = 0
  int ln = threadIdx.x;
  float acc = 0.f;
  for (int d = ln; d < D_; d += 64) acc += ctx[(size_t)m * D_ + d] * wg[g * D_ + d];
#pragma unroll
  for (int msk = 32; msk >= 1; msk >>= 1) acc += __shfl_xor(acc, msk);
  if (ln == 0) out_gate[id] = acc + wgb[g];
}

// ---------- scale one row by p_gen/rowsum (rowsum from partials) ----------
__global__ void k_scale(float* __restrict__ out, const float* __restrict__ p_gen,
                        const float* __restrict__ part) {
  int m = blockIdx.x;
  int tid = threadIdx.x, ln = tid & 63, w = tid >> 6;
  float ps = (tid < NT_) ? part[(size_t)tid * M_ + m] : 0.f;
#pragma unroll
  for (int msk = 32; msk >= 1; msk >>= 1) ps += __shfl_xor(ps, msk);
  __shared__ float red[4];
  __shared__ float scs;
  if (ln == 0) red[w] = ps;
  __syncthreads();
  if (tid == 0) scs = p_gen[m] / (red[0] + red[1] + red[2] + red[3]);
  __syncthreads();
  float sc = scs;
  int b = m >> 7, s = (m >> 3) & 15, l = m & 7;
  float4* p = (float4*)(out + (size_t)((s * B_ + b) * L_ + l) * (size_t)V_);
  for (int j = tid; j < V_ / 4; j += 256) {
    float4 v = p[j];
    v.x *= sc; v.y *= sc; v.z *= sc; v.w *= sc;
    p[j] = v;
  }
}

// ---------- copy-distribution scatter ----------
__global__ void k_scatter(float* __restrict__ out, const float* __restrict__ p_gen,
                          const float* __restrict__ probs, const int* __restrict__ story) {
  int id = blockIdx.x * 256 + threadIdx.x;  // < M_*T_
  int m = id >> 9, t = id & 511;
  int b = m >> 7, s = (m >> 3) & 15, l = m & 7;
  float val = (1.f - p_gen[m]) * probs[(size_t)m * T_ + t];
  int v = story[b * T_ + t];
  size_t o = (size_t)((s * B_ + b) * L_ + l) * (size_t)V_ + v;
  atomicAdd(out + o, val);
}

extern "C" void kernel_launch(void* const* d_in, const int* in_sizes, int n_in,
                              void* d_out, int out_size, void* d_ws, size_t ws_size,
                              hipStream_t stream) {
  (void)in_sizes; (void)n_in; (void)out_size; (void)ws_size;
  const float* enc_hid   = (const float*)d_in[0];
  const float* enc_out   = (const float*)d_in[1];
  const int*   story     = (const int*)d_in[2];
  const int*   trg       = (const int*)d_in[3];
  const float* emb       = (const float*)d_in[4];
  const float* w_ih      = (const float*)d_in[5];
  const float* w_hh      = (const float*)d_in[6];
  const float* b_ih      = (const float*)d_in[7];
  const float* b_hh      = (const float*)d_in[8];
  const float* w_ratio_w = (const float*)d_in[9];
  const float* w_ratio_b = (const float*)d_in[10];
  const float* w_gate_w  = (const float*)d_in[11];
  const float* w_gate_b  = (const float*)d_in[12];
  const float* slot_emb  = (const float*)d_in[13];
  float* out = (float*)d_out;

  char* ws = (char*)d_ws;
  size_t off = 0;
  auto alloc = [&](size_t bytes) -> void* {
    void* p = ws + off;
    off += (bytes + 255) & ~(size_t)255;
    return p;
  };
  U16* emb_bf   = (U16*)alloc((size_t)V_ * D_ * 2);
  float* x      = (float*)alloc((size_t)M_ * D_ * 4);
  U16* x_h      = (U16*)alloc((size_t)M_ * D_ * 2);
  U16* x_l      = (U16*)alloc((size_t)M_ * D_ * 2);
  U16* wih_h    = (U16*)alloc((size_t)E3_ * D_ * 2);
  U16* wih_l    = (U16*)alloc((size_t)E3_ * D_ * 2);
  U16* enc_h    = (U16*)alloc((size_t)B_ * T_ * D_ * 2);
  U16* enc_l    = (U16*)alloc((size_t)B_ * T_ * D_ * 2);
  U16* encT_h   = (U16*)alloc((size_t)B_ * T_ * D_ * 2);
  U16* encT_l   = (U16*)alloc((size_t)B_ * T_ * D_ * 2);
  float* gh     = (float*)alloc((size_t)B_ * E3_ * 4);
  float* gi     = (float*)alloc((size_t)M_ * E3_ * 4);
  float* h      = (float*)alloc((size_t)M_ * D_ * 4);
  U16* h_h      = (U16*)alloc((size_t)M_ * D_ * 2);
  U16* h_l      = (U16*)alloc((size_t)M_ * D_ * 2);
  float* scores = (float*)alloc((size_t)M_ * T_ * 4);
  U16* sc_h     = (U16*)alloc((size_t)M_ * T_ * 2);
  U16* sc_l     = (U16*)alloc((size_t)M_ * T_ * 2);
  float* probs  = (float*)alloc((size_t)M_ * T_ * 4);
  float* ctx    = (float*)alloc((size_t)M_ * D_ * 4);
  float* p_gen  = (float*)alloc((size_t)M_ * 4);
  float* part   = (float*)alloc((size_t)NT_ * M_ * 4);

  // --- casts / prep ---
  k_cast_emb<<<V_ * D_ / 4 / 256, 256, 0, stream>>>(emb, emb_bf);
  k_cast_wih<<<E3_ * D_ / 4 / 256, 256, 0, stream>>>(w_ih, wih_h, wih_l);
  k_cast_enc<<<dim3(T_ / 32, D_ / 32, B_), 256, 0, stream>>>(enc_out, enc_h, enc_l, encT_h, encT_l);
  k_build_x<<<M_, 256, 0, stream>>>(emb, slot_emb, trg, x, x_h, x_l);
  k_gh<<<dim3(E3_ / 64, B_), 256, 0, stream>>>(enc_hid, w_hh, b_hh, gh);

  // --- gi = x @ w_ih^T (hi/lo) ---
  k_gemm<32, true, false, false><<<dim3(E3_ / 128, M_ / 128, 1), 256, 0, stream>>>(
      x_h, x_l, wih_h, wih_l, gi, nullptr, D_, D_, D_, E3_, 0, 0, 0);

  // --- GRU pointwise -> h ---
  k_h<<<M_, 256, 0, stream>>>(gi, gh, enc_hid, b_ih, h, h_h, h_l);

  // --- scores = h @ enc^T per batch (hi/lo) ---
  k_gemm<32, true, false, false><<<dim3(T_ / 128, 1, B_), 256, 0, stream>>>(
      h_h, h_l, enc_h, enc_l, scores, nullptr, D_, D_, D_, T_,
      (long)(S_ * L_) * D_, (long)T_ * D_, (long)(S_ * L_) * T_);

  // --- softmax over T + score splits ---
  k_softmax<<<M_, 256, 0, stream>>>(scores, probs, sc_h, sc_l);

  // --- context = scores @ enc per batch (hi/lo, B from transposed enc) ---
  k_gemm<32, true, false, false><<<dim3(D_ / 128, 1, B_), 256, 0, stream>>>(
      sc_h, sc_l, encT_h, encT_l, ctx, nullptr, T_, T_, T_, D_,
      (long)(S_ * L_) * T_, (long)D_ * T_, (long)(S_ * L_) * D_);

  // --- p_gen, gate outputs ---
  k_pgen<<<M_, 256, 0, stream>>>(h, ctx, x, w_ratio_w, w_ratio_b, p_gen);
  k_gate<<<S_ * B_ * G_, 64, 0, stream>>>(ctx, w_gate_w, w_gate_b, out + (size_t)M_ * V_);

  // --- vocab GEMM: out = exp(h @ E^T), m-tile fastest for B-tile L2 reuse, BK=64 ---
  k_gemm<64, false, true, true><<<dim3(M_ / 128, V_ / 128, 1), 256, 0, stream>>>(
      h_h, nullptr, emb_bf, nullptr, out, part, D_, D_, D_, V_, 0, 0, 0);

  // --- per-row: rowsum from partials, scale by p_gen/rowsum ; then scatter copy-probs ---
  k_scale<<<M_, 256, 0, stream>>>(out, p_gen, part);
  k_scatter<<<M_ * T_ / 256, 256, 0, stream>>>(out, p_gen, probs, story);
}

// Round 3
// 585.566 us; speedup vs baseline: 1.1491x; 1.0139x over previous
//
#include <hip/hip_runtime.h>

// Problem constants
#define S_ 16
#define B_ 8
#define L_ 8
#define V_ 32000
#define D_ 1024
#define T_ 512
#define G_ 3
#define M_ 1024          // B*S*L fused row count, m = ((b*S + s)*L + l)
#define E3_ 3072         // 3*D
#define NT_ 250          // V_/128 n-tiles in vocab GEMM

typedef unsigned short U16;
typedef __attribute__((ext_vector_type(8))) short short8;
typedef __attribute__((ext_vector_type(4))) float f32x4;

// ---------- bf16 helpers (RTNE) ----------
__device__ __forceinline__ U16 f2bf(float f) {
  union { float f; unsigned u; } c; c.f = f;
  unsigned u = c.u;
  return (U16)((u + 0x7FFFu + ((u >> 16) & 1u)) >> 16);
}
__device__ __forceinline__ float bf2f(U16 h) {
  union { unsigned u; float f; } c; c.u = ((unsigned)h) << 16;
  return c.f;
}
__device__ __forceinline__ void split2(float f, U16& hi, U16& lo) {
  hi = f2bf(f);
  lo = f2bf(f - bf2f(hi));
}

// ---------- cast kernels ----------
__global__ void k_cast_emb(const float* __restrict__ emb, U16* __restrict__ emb_bf) {
  int idx = blockIdx.x * 256 + threadIdx.x;      // < V_*D_/4
  float4 v = ((const float4*)emb)[idx];
  ushort4 o;
  o.x = f2bf(v.x); o.y = f2bf(v.y); o.z = f2bf(v.z); o.w = f2bf(v.w);
  ((ushort4*)emb_bf)[idx] = o;
}

__global__ void k_cast_wih(const float* __restrict__ w, U16* __restrict__ wh, U16* __restrict__ wl) {
  int idx = blockIdx.x * 256 + threadIdx.x;      // < E3_*D_/4
  float4 v = ((const float4*)w)[idx];
  ushort4 h4, l4;
  split2(v.x, h4.x, l4.x); split2(v.y, h4.y, l4.y);
  split2(v.z, h4.z, l4.z); split2(v.w, h4.w, l4.w);
  ((ushort4*)wh)[idx] = h4;
  ((ushort4*)wl)[idx] = l4;
}

// x[m,:] = (l==0) ? slot_emb[s] : embedding[trg[b,s,l-1]]
__global__ void k_build_x(const float* __restrict__ emb, const float* __restrict__ slot_emb,
                          const int* __restrict__ trg, float* __restrict__ x,
                          U16* __restrict__ x_h, U16* __restrict__ x_l) {
  int m = blockIdx.x;
  int d = threadIdx.x * 4;
  int b = m >> 7, s = (m >> 3) & 15, l = m & 7;
  const float* src;
  if (l == 0) src = slot_emb + s * D_;
  else        src = emb + (size_t)trg[b * (S_ * L_) + s * L_ + (l - 1)] * D_;
  float4 v = *(const float4*)(src + d);
  *(float4*)(x + (size_t)m * D_ + d) = v;
  ushort4 h4, l4;
  split2(v.x, h4.x, l4.x); split2(v.y, h4.y, l4.y);
  split2(v.z, h4.z, l4.z); split2(v.w, h4.w, l4.w);
  *(ushort4*)(x_h + (size_t)m * D_ + d) = h4;
  *(ushort4*)(x_l + (size_t)m * D_ + d) = l4;
}

// gh[b,e] = sum_d h0[b,d]*w_hh[e,d] + b_hh[e]   (fp32 exact path)
__global__ void k_gh(const float* __restrict__ h0, const float* __restrict__ w_hh,
                     const float* __restrict__ b_hh, float* __restrict__ gh) {
  int b = blockIdx.y;
  int e = blockIdx.x * 64 + (threadIdx.x >> 2);
  int part = threadIdx.x & 3;
  const float* hr = h0 + b * D_ + part * 256;
  const float* wr = w_hh + (size_t)e * D_ + part * 256;
  float s = 0.f;
  for (int i = 0; i < 256; ++i) s += hr[i] * wr[i];
  s += __shfl_xor(s, 1);
  s += __shfl_xor(s, 2);
  if (part == 0) gh[b * E3_ + e] = s + b_hh[e];
}

// ---------- MFMA GEMM: C[m,n] = sum_k A[m,k]*B[n,k], 128x128 tile, BK=64 ----------
// BK=64 layout: row = 128B (8 chunks of 16B), chunk XOR row&7
template <int BK>
__device__ __forceinline__ void stage_tile(U16* __restrict__ sm, const U16* __restrict__ g,
                                           int row0, int k0, int lda, int tid) {
  constexpr int PASSES = (128 * BK * 2) / 4096;   // 256 threads * 16B per pass
#pragma unroll
  for (int i = 0; i < PASSES; ++i) {
    int o = (i * 256 + tid) * 16;                 // byte offset in tile
    int row = o >> 7;
    int gc = ((o >> 4) & 7) ^ (row & 7);
    const U16* gp = g + (size_t)(row0 + row) * lda + k0 + gc * 8;
    U16* sp = sm + (o >> 1);
    __builtin_amdgcn_global_load_lds((const __attribute__((address_space(1))) unsigned int*)gp,
                                     (__attribute__((address_space(3))) unsigned int*)sp,
                                     16, 0, 0);
  }
}

template <int BK>
__device__ __forceinline__ short8 frag_ld(const U16* __restrict__ sm, int rowbase, int ln, int kh) {
  int row = rowbase + (ln & 15);
  int c = (kh * 4 + (ln >> 4)) ^ (row & 7);
  return *(const short8*)(sm + row * 64 + c * 8);
}

template <int BK, bool HILO, bool VOCAB>
__global__ __launch_bounds__(256, 2)
void k_gemm(const U16* __restrict__ Ah, const U16* __restrict__ Al,
            const U16* __restrict__ Bh, const U16* __restrict__ Bl,
            float* __restrict__ C, float* __restrict__ part,
            int Ktot, int lda, int ldb, int ldc) {
  constexpr int TILE_U16 = 128 * BK;
  __shared__ U16 smem[(HILO ? 4 : 2) * TILE_U16];
  __shared__ float rsred[128];
  U16* Ash = smem;
  U16* Bsh = smem + TILE_U16;
  U16* Asl = HILO ? (smem + 2 * TILE_U16) : smem;
  U16* Bsl = HILO ? (smem + 3 * TILE_U16) : smem;

  int tid = threadIdx.x;
  int ln = tid & 63, w = tid >> 6;
  int wr = (w >> 1) * 64, wc = (w & 1) * 64;
  int m0, n0, ntile = 0;
  if constexpr (VOCAB) {
    // XCD-affine: bid&7 = XCD (round-robin dispatch). Give each XCD a
    // contiguous n-tile range; the 8 m-blocks of one n-tile stay on one XCD
    // and run back-to-back -> B-tile fetched from HBM once, reused in L2.
    int bid = blockIdx.x;
    int tile = (bid & 7) * NT_ + (bid >> 3);
    ntile = tile >> 3;
    m0 = (tile & 7) * 128;
    n0 = ntile * 128;
  } else {
    m0 = blockIdx.y * 128;
    n0 = blockIdx.x * 128;
  }

  if constexpr (VOCAB) {
    if (tid < 128) rsred[tid] = 0.f;
  }

  f32x4 acc[4][4];
#pragma unroll
  for (int i = 0; i < 4; i++)
#pragma unroll
    for (int j = 0; j < 4; j++) acc[i][j] = (f32x4)(0.f);

  for (int k0 = 0; k0 < Ktot; k0 += BK) {
    __syncthreads();                        // protect LDS from prior reads
    stage_tile<BK>(Ash, Ah, m0, k0, lda, tid);
    stage_tile<BK>(Bsh, Bh, n0, k0, ldb, tid);
    if constexpr (HILO) {
      stage_tile<BK>(Asl, Al, m0, k0, lda, tid);
      stage_tile<BK>(Bsl, Bl, n0, k0, ldb, tid);
    }
    __syncthreads();                        // drains vmcnt(0) incl. global_load_lds

#pragma unroll
    for (int kh = 0; kh < BK / 32; kh++) {
      short8 a_h[4], b_h[4];
#pragma unroll
      for (int i = 0; i < 4; i++) {
        a_h[i] = frag_ld<BK>(Ash, wr + i * 16, ln, kh);
        b_h[i] = frag_ld<BK>(Bsh, wc + i * 16, ln, kh);
      }
      if constexpr (HILO) {
        short8 a_l[4], b_l[4];
#pragma unroll
        for (int i = 0; i < 4; i++) {
          a_l[i] = frag_ld<BK>(Asl, wr + i * 16, ln, kh);
          b_l[i] = frag_ld<BK>(Bsl, wc + i * 16, ln, kh);
        }
#pragma unroll
        for (int i = 0; i < 4; i++)
#pragma unroll
          for (int j = 0; j < 4; j++) {
            acc[i][j] = __builtin_amdgcn_mfma_f32_16x16x32_bf16(a_h[i], b_h[j], acc[i][j], 0, 0, 0);
            acc[i][j] = __builtin_amdgcn_mfma_f32_16x16x32_bf16(a_h[i], b_l[j], acc[i][j], 0, 0, 0);
            acc[i][j] = __builtin_amdgcn_mfma_f32_16x16x32_bf16(a_l[i], b_h[j], acc[i][j], 0, 0, 0);
          }
      } else {
#pragma unroll
        for (int i = 0; i < 4; i++)
#pragma unroll
          for (int j = 0; j < 4; j++)
            acc[i][j] = __builtin_amdgcn_mfma_f32_16x16x32_bf16(a_h[i], b_h[j], acc[i][j], 0, 0, 0);
      }
    }
  }

  int quad = ln >> 4, col = ln & 15;
  if constexpr (!VOCAB) {
#pragma unroll
    for (int i = 0; i < 4; i++)
#pragma unroll
      for (int j = 0; j < 4; j++)
#pragma unroll
        for (int r = 0; r < 4; r++)
          C[(size_t)(m0 + wr + i * 16 + quad * 4 + r) * ldc + (n0 + wc + j * 16 + col)] =
              acc[i][j][r];
  } else {
    // out[((s*B+b)*L+l)*V + v] = exp(logit); per-(ntile,row) partial sums
#pragma unroll
    for (int i = 0; i < 4; i++)
#pragma unroll
      for (int r = 0; r < 4; r++) {
        int m = m0 + wr + i * 16 + quad * 4 + r;
        int s_ = (m >> 3) & 15, l_ = m & 7, b_ = m >> 7;
        size_t obase = (size_t)((s_ * B_ + b_) * L_ + l_) * (size_t)V_;
        float rs = 0.f;
#pragma unroll
        for (int j = 0; j < 4; j++) {
          float e = __expf(acc[i][j][r]);
          C[obase + (n0 + wc + j * 16 + col)] = e;
          rs += e;
        }
        rs += __shfl_xor(rs, 1);
        rs += __shfl_xor(rs, 2);
        rs += __shfl_xor(rs, 4);
        rs += __shfl_xor(rs, 8);
        if (col == 0) atomicAdd(&rsred[(wr + i * 16 + quad * 4 + r)], rs);  // LDS atomic
      }
    __syncthreads();
    if (tid < 128) part[(size_t)ntile * M_ + (m0 + tid)] = rsred[tid];
  }
}

// ---------- GRU pointwise ----------
__global__ void k_h(const float* __restrict__ gi, const float* __restrict__ gh,
                    const float* __restrict__ h0, const float* __restrict__ b_ih,
                    float* __restrict__ h, U16* __restrict__ h_h) {
  int m = blockIdx.x;
  int d = threadIdx.x * 4;
  int b = m >> 7;
  float4 ir  = *(const float4*)(gi + (size_t)m * E3_ + d);
  float4 iz  = *(const float4*)(gi + (size_t)m * E3_ + D_ + d);
  float4 in_ = *(const float4*)(gi + (size_t)m * E3_ + 2 * D_ + d);
  float4 bir = *(const float4*)(b_ih + d);
  float4 biz = *(const float4*)(b_ih + D_ + d);
  float4 bin = *(const float4*)(b_ih + 2 * D_ + d);
  float4 hr  = *(const float4*)(gh + b * E3_ + d);
  float4 hz  = *(const float4*)(gh + b * E3_ + D_ + d);
  float4 hn  = *(const float4*)(gh + b * E3_ + 2 * D_ + d);
  float4 h0v = *(const float4*)(h0 + b * D_ + d);
  float4 out;
#define GRU1(c)                                             \
  {                                                         \
    float rr = 1.f / (1.f + __expf(-(ir.c + bir.c + hr.c))); \
    float zz = 1.f / (1.f + __expf(-(iz.c + biz.c + hz.c))); \
    float nn = tanhf(in_.c + bin.c + rr * hn.c);            \
    out.c = (1.f - zz) * nn + zz * h0v.c;                   \
  }
  GRU1(x) GRU1(y) GRU1(z) GRU1(w)
#undef GRU1
  *(float4*)(h + (size_t)m * D_ + d) = out;
  ushort4 h4;
  h4.x = f2bf(out.x); h4.y = f2bf(out.y); h4.z = f2bf(out.z); h4.w = f2bf(out.w);
  *(ushort4*)(h_h + (size_t)m * D_ + d) = h4;
}

// ---------- scores = h @ enc^T, exact fp32 ----------
// grid (4 t-chunks, 16 m-chunks of 8 rows, 8 b), 256 thr
__global__ void k_scores(const float* __restrict__ h, const float* __restrict__ enc,
                         float* __restrict__ scores) {
  __shared__ float hs[8 * D_];
  int t0 = blockIdx.x * 128, mc = blockIdx.y, b = blockIdx.z;
  int tid = threadIdx.x;
  int mbase = b * 128 + mc * 8;
  const float4* hsrc = (const float4*)(h + (size_t)mbase * D_);
  float4* hs4 = (float4*)hs;
  for (int i = tid; i < 8 * D_ / 4; i += 256) hs4[i] = hsrc[i];
  __syncthreads();
  int j = tid & 127, rg = (tid >> 7) * 4;
  const float4* e4 = (const float4*)(enc + ((size_t)b * T_ + t0 + j) * D_);
  const float4* h0p = (const float4*)(hs + (rg + 0) * D_);
  const float4* h1p = (const float4*)(hs + (rg + 1) * D_);
  const float4* h2p = (const float4*)(hs + (rg + 2) * D_);
  const float4* h3p = (const float4*)(hs + (rg + 3) * D_);
  float a0 = 0.f, a1 = 0.f, a2 = 0.f, a3 = 0.f;
#pragma unroll 4
  for (int k = 0; k < D_ / 4; k++) {
    float4 e = e4[k];
    float4 v0 = h0p[k], v1 = h1p[k], v2 = h2p[k], v3 = h3p[k];
    a0 += e.x * v0.x + e.y * v0.y + e.z * v0.z + e.w * v0.w;
    a1 += e.x * v1.x + e.y * v1.y + e.z * v1.z + e.w * v1.w;
    a2 += e.x * v2.x + e.y * v2.y + e.z * v2.z + e.w * v2.w;
    a3 += e.x * v3.x + e.y * v3.y + e.z * v3.z + e.w * v3.w;
  }
  scores[(size_t)(mbase + rg + 0) * T_ + t0 + j] = a0;
  scores[(size_t)(mbase + rg + 1) * T_ + t0 + j] = a1;
  scores[(size_t)(mbase + rg + 2) * T_ + t0 + j] = a2;
  scores[(size_t)(mbase + rg + 3) * T_ + t0 + j] = a3;
}

// ---------- context = raw_scores @ enc, exact fp32 ----------
// grid (8 d-chunks, 16 m-chunks of 8 rows, 8 b), 256 thr
__global__ void k_ctx(const float* __restrict__ scores, const float* __restrict__ enc,
                      float* __restrict__ ctx) {
  __shared__ float ss[8 * T_];
  int d0 = blockIdx.x * 128, mc = blockIdx.y, b = blockIdx.z;
  int tid = threadIdx.x;
  int mbase = b * 128 + mc * 8;
  const float4* ssrc = (const float4*)(scores + (size_t)mbase * T_);
  float4* ss4 = (float4*)ss;
  for (int i = tid; i < 8 * T_ / 4; i += 256) ss4[i] = ssrc[i];
  __syncthreads();
  int j = tid & 127, rg = (tid >> 7) * 4;
  int d = d0 + j;
  const float* s0 = ss + (rg + 0) * T_;
  const float* s1 = ss + (rg + 1) * T_;
  const float* s2 = ss + (rg + 2) * T_;
  const float* s3 = ss + (rg + 3) * T_;
  float a0 = 0.f, a1 = 0.f, a2 = 0.f, a3 = 0.f;
#pragma unroll 8
  for (int t = 0; t < T_; t++) {
    float e = enc[((size_t)b * T_ + t) * D_ + d];
    a0 += e * s0[t];
    a1 += e * s1[t];
    a2 += e * s2[t];
    a3 += e * s3[t];
  }
  ctx[(size_t)(mbase + rg + 0) * D_ + d] = a0;
  ctx[(size_t)(mbase + rg + 1) * D_ + d] = a1;
  ctx[(size_t)(mbase + rg + 2) * D_ + d] = a2;
  ctx[(size_t)(mbase + rg + 3) * D_ + d] = a3;
}

// ---------- softmax over T ----------
__global__ void k_softmax(const float* __restrict__ scores, float* __restrict__ probs) {
  int m = blockIdx.x;
  int tid = threadIdx.x;
  int ln = tid & 63, w = tid >> 6;
  float v0 = scores[(size_t)m * T_ + tid];
  float v1 = scores[(size_t)m * T_ + 256 + tid];
  float mx = fmaxf(v0, v1);
#pragma unroll
  for (int msk = 32; msk >= 1; msk >>= 1) mx = fmaxf(mx, __shfl_xor(mx, msk));
  __shared__ float red[4];
  if (ln == 0) red[w] = mx;
  __syncthreads();
  mx = fmaxf(fmaxf(red[0], red[1]), fmaxf(red[2], red[3]));
  float e0 = __expf(v0 - mx), e1 = __expf(v1 - mx);
  float sm = e0 + e1;
#pragma unroll
  for (int msk = 32; msk >= 1; msk >>= 1) sm += __shfl_xor(sm, msk);
  __syncthreads();
  if (ln == 0) red[w] = sm;
  __syncthreads();
  float inv = 1.f / (red[0] + red[1] + red[2] + red[3]);
  probs[(size_t)m * T_ + tid] = e0 * inv;
  probs[(size_t)m * T_ + 256 + tid] = e1 * inv;
}

// ---------- p_gen (accurate fp32 dot) ----------
__global__ void k_pgen(const float* __restrict__ h, const float* __restrict__ ctx,
                       const float* __restrict__ x, const float* __restrict__ wr,
                       const float* __restrict__ wrb, float* __restrict__ p_gen) {
  int m = blockIdx.x;
  int tid = threadIdx.x;
  int ln = tid & 63, w = tid >> 6;
  float sacc = 0.f;
  for (int j = tid; j < D_; j += 256)
    sacc += h[(size_t)m * D_ + j] * wr[j] + ctx[(size_t)m * D_ + j] * wr[D_ + j] +
            x[(size_t)m * D_ + j] * wr[2 * D_ + j];
#pragma unroll
  for (int msk = 32; msk >= 1; msk >>= 1) sacc += __shfl_xor(sacc, msk);
  __shared__ float red[4];
  if (ln == 0) red[w] = sacc;
  __syncthreads();
  if (tid == 0) {
    float t = red[0] + red[1] + red[2] + red[3] + wrb[0];
    p_gen[m] = 1.f / (1.f + expf(-t));
  }
}

// ---------- gate_outputs ----------
__global__ void k_gate(const float* __restrict__ ctx, const float* __restrict__ wg,
                       const float* __restrict__ wgb, float* __restrict__ out_gate) {
  int id = blockIdx.x;                // (s*8+b)*3+g
  int g = id % 3;
  int sb = id / 3;
  int b = sb & 7, s = sb >> 3;
  int m = (b * S_ + s) * L_;          // l = 0
  int ln = threadIdx.x;
  float acc = 0.f;
  for (int d = ln; d < D_; d += 64) acc += ctx[(size_t)m * D_ + d] * wg[g * D_ + d];
#pragma unroll
  for (int msk = 32; msk >= 1; msk >>= 1) acc += __shfl_xor(acc, msk);
  if (ln == 0) out_gate[id] = acc + wgb[g];
}

// ---------- per-row: rowsum from partials, scale by p_gen/rowsum, then scatter ----------
__global__ void k_scale(float* __restrict__ out, const float* __restrict__ p_gen,
                        const float* __restrict__ part, const float* __restrict__ probs,
                        const int* __restrict__ story) {
  int m = blockIdx.x;
  int tid = threadIdx.x, ln = tid & 63, w = tid >> 6;
  float ps = (tid < NT_) ? part[(size_t)tid * M_ + m] : 0.f;
#pragma unroll
  for (int msk = 32; msk >= 1; msk >>= 1) ps += __shfl_xor(ps, msk);
  __shared__ float red[4];
  __shared__ float scs;
  if (ln == 0) red[w] = ps;
  __syncthreads();
  if (tid == 0) scs = p_gen[m] / (red[0] + red[1] + red[2] + red[3]);
  __syncthreads();
  float sc = scs;
  int b = m >> 7, s = (m >> 3) & 15, l = m & 7;
  float* row = out + (size_t)((s * B_ + b) * L_ + l) * (size_t)V_;
  float4* p = (float4*)row;
  for (int j = tid; j < V_ / 4; j += 256) {
    float4 v = p[j];
    v.x *= sc; v.y *= sc; v.z *= sc; v.w *= sc;
    p[j] = v;
  }
  __syncthreads();   // vmcnt(0) drain: scaled stores visible in L2 before atomics
  float om = 1.f - p_gen[m];
  for (int t = tid; t < T_; t += 256)
    atomicAdd(row + story[b * T_ + t], om * probs[(size_t)m * T_ + t]);
}

extern "C" void kernel_launch(void* const* d_in, const int* in_sizes, int n_in,
                              void* d_out, int out_size, void* d_ws, size_t ws_size,
                              hipStream_t stream) {
  (void)in_sizes; (void)n_in; (void)out_size; (void)ws_size;
  const float* enc_hid   = (const float*)d_in[0];
  const float* enc_out   = (const float*)d_in[1];
  const int*   story     = (const int*)d_in[2];
  const int*   trg       = (const int*)d_in[3];
  const float* emb       = (const float*)d_in[4];
  const float* w_ih      = (const float*)d_in[5];
  const float* w_hh      = (const float*)d_in[6];
  const float* b_ih      = (const float*)d_in[7];
  const float* b_hh      = (const float*)d_in[8];
  const float* w_ratio_w = (const float*)d_in[9];
  const float* w_ratio_b = (const float*)d_in[10];
  const float* w_gate_w  = (const float*)d_in[11];
  const float* w_gate_b  = (const float*)d_in[12];
  const float* slot_emb  = (const float*)d_in[13];
  float* out = (float*)d_out;

  char* ws = (char*)d_ws;
  size_t off = 0;
  auto alloc = [&](size_t bytes) -> void* {
    void* p = ws + off;
    off += (bytes + 255) & ~(size_t)255;
    return p;
  };
  U16* emb_bf   = (U16*)alloc((size_t)V_ * D_ * 2);
  float* x      = (float*)alloc((size_t)M_ * D_ * 4);
  U16* x_h      = (U16*)alloc((size_t)M_ * D_ * 2);
  U16* x_l      = (U16*)alloc((size_t)M_ * D_ * 2);
  U16* wih_h    = (U16*)alloc((size_t)E3_ * D_ * 2);
  U16* wih_l    = (U16*)alloc((size_t)E3_ * D_ * 2);
  float* gh     = (float*)alloc((size_t)B_ * E3_ * 4);
  float* gi     = (float*)alloc((size_t)M_ * E3_ * 4);
  float* h      = (float*)alloc((size_t)M_ * D_ * 4);
  U16* h_h      = (U16*)alloc((size_t)M_ * D_ * 2);
  float* scores = (float*)alloc((size_t)M_ * T_ * 4);
  float* probs  = (float*)alloc((size_t)M_ * T_ * 4);
  float* ctx    = (float*)alloc((size_t)M_ * D_ * 4);
  float* p_gen  = (float*)alloc((size_t)M_ * 4);
  float* part   = (float*)alloc((size_t)NT_ * M_ * 4);

  // --- casts / prep ---
  k_cast_emb<<<V_ * D_ / 4 / 256, 256, 0, stream>>>(emb, emb_bf);
  k_cast_wih<<<E3_ * D_ / 4 / 256, 256, 0, stream>>>(w_ih, wih_h, wih_l);
  k_build_x<<<M_, 256, 0, stream>>>(emb, slot_emb, trg, x, x_h, x_l);
  k_gh<<<dim3(E3_ / 64, B_), 256, 0, stream>>>(enc_hid, w_hh, b_hh, gh);

  // --- gi = x @ w_ih^T (hi/lo MFMA, BK=64) ---
  k_gemm<64, true, false><<<dim3(E3_ / 128, M_ / 128), 256, 0, stream>>>(
      x_h, x_l, wih_h, wih_l, gi, nullptr, D_, D_, D_, E3_);

  // --- GRU pointwise -> h ---
  k_h<<<M_, 256, 0, stream>>>(gi, gh, enc_hid, b_ih, h, h_h);

  // --- scores (fp32 exact) ---
  k_scores<<<dim3(4, 16, 8), 256, 0, stream>>>(h, enc_out, scores);

  // --- softmax over T ---
  k_softmax<<<M_, 256, 0, stream>>>(scores, probs);

  // --- context from raw scores (fp32 exact) ---
  k_ctx<<<dim3(8, 16, 8), 256, 0, stream>>>(scores, enc_out, ctx);

  // --- p_gen, gate outputs ---
  k_pgen<<<M_, 256, 0, stream>>>(h, ctx, x, w_ratio_w, w_ratio_b, p_gen);
  k_gate<<<S_ * B_ * G_, 64, 0, stream>>>(ctx, w_gate_w, w_gate_b, out + (size_t)M_ * V_);

  // --- vocab GEMM: out = exp(h @ E^T), XCD-affine 1D grid, BK=64 ---
  k_gemm<64, false, true><<<dim3(8 * NT_), 256, 0, stream>>>(
      h_h, nullptr, emb_bf, nullptr, out, part, D_, D_, D_, V_);

  // --- per-row: rowsum, scale, scatter (fused) ---
  k_scale<<<M_, 256, 0, stream>>>(out, p_gen, part, probs, story);
}